// Round 1
// baseline (21728.041 us; speedup 1.0000x reference)
//
#include <hip/hip_runtime.h>
#include <hip/hip_fp16.h>
#include <hip/hip_cooperative_groups.h>

namespace cg = cooperative_groups;

typedef _Float16 f16;
typedef _Float16 f16x8 __attribute__((ext_vector_type(8)));
typedef _Float16 f16x4 __attribute__((ext_vector_type(4)));
typedef float    f32x4 __attribute__((ext_vector_type(4)));

#define LN_EPS 1e-6f
// B=16 S=512 H=1024 V=32000 L=2

// ---------------------------------------------------------------------------
// A1: embed fp32 -> f16 copy (for logits GEMM B operand)
__global__ void k_cvt(const float* __restrict__ in, f16* __restrict__ out, int n4) {
    int i = blockIdx.x * 256 + threadIdx.x;
    int st = gridDim.x * 256;
    for (; i < n4; i += st) {
        float4 v = ((const float4*)in)[i];
        f16x4 o = { (f16)v.x, (f16)v.y, (f16)v.z, (f16)v.w };
        ((f16x4*)out)[i] = o;
    }
}

// ---------------------------------------------------------------------------
// A2: per-(t,b) LayerNorm stats of the embedding rows (layer-0 input)
__global__ void k_xstat(const int* __restrict__ x, const float* __restrict__ embed,
                        float2* __restrict__ xstat) {
    int r = blockIdx.x * 4 + (threadIdx.x >> 6);   // r = t*16 + b, 8192 rows
    int lane = threadIdx.x & 63;
    int t = r >> 4, b = r & 15;
    int tok = x[b * 512 + t];
    const float4* p = (const float4*)(embed + (size_t)tok * 1024);
    float sum = 0.f, sq = 0.f;
    #pragma unroll
    for (int j = 0; j < 4; ++j) {
        float4 v = p[lane * 4 + j];
        sum += v.x + v.y + v.z + v.w;
        sq  += v.x*v.x + v.y*v.y + v.z*v.z + v.w*v.w;
    }
    #pragma unroll
    for (int m = 1; m < 64; m <<= 1) {
        sum += __shfl_xor(sum, m);
        sq  += __shfl_xor(sq,  m);
    }
    if (lane == 0) {
        float mu  = sum * (1.f / 1024.f);
        float var = sq  * (1.f / 1024.f) - mu * mu;
        xstat[r] = make_float2(mu, rsqrtf(var + LN_EPS));
    }
}

// ---------------------------------------------------------------------------
// C: persistent cooperative recurrence. 256 blocks x 256 threads.
// blocks [0,128): layer 0 (step = tick); blocks [128,256): layer 1 (step = tick-1).
// Each block owns 8 hidden units of its layer; W slice (f16) resident in LDS.
// LDS: Wlds[2][32][1024] f16 (XOR-swizzled) = 131072B, zred[4][16][32] f32 = 8192B,
//      stats[16][2] f32 = 128B  -> 139392B total.
__global__ void __launch_bounds__(256, 1)
k_recur(const int* __restrict__ x, const float* __restrict__ embed,
        const float* __restrict__ gamma, const float* __restrict__ beta,
        const float* __restrict__ W, const float* __restrict__ bias,
        const float2* __restrict__ xstat,
        f16* __restrict__ h0buf, f16* __restrict__ h1buf,   // [2][16][1024]
        float* __restrict__ inp1buf,                        // [2][16][1024]
        f16* __restrict__ hseq,                             // [512*16][1024]
        float* __restrict__ cout)                           // [2][16][1024]
{
    extern __shared__ char smem[];
    float* zred  = (float*)(smem + 131072);
    float* stats = (float*)(smem + 131072 + 8192);

    const int tid   = threadIdx.x;
    const int lane  = tid & 63;
    const int wv    = tid >> 6;
    const int blk   = blockIdx.x;
    const int layer = (blk < 128) ? 0 : 1;
    const int base  = (layer ? blk - 128 : blk) * 8;   // global unit base (8 units)

    // ---- preload W slice -> LDS f16, layout [mat][lc][k], lc = gate*8+u, swizzled
    {
        const float* Wm = W + (size_t)layer * 2048 * 4096;
        for (int idx = tid; idx < 2048; idx += 256) {
            const int mat = idx >> 10;          // 0 = xn-part, 1 = h-part
            const int k   = idx & 1023;
            const float* row = Wm + (size_t)(mat * 1024 + k) * 4096 + base;
            #pragma unroll
            for (int g = 0; g < 4; ++g) {
                float4 a = *(const float4*)(row + g * 1024);
                float4 c = *(const float4*)(row + g * 1024 + 4);
                float vals[8] = {a.x, a.y, a.z, a.w, c.x, c.y, c.z, c.w};
                #pragma unroll
                for (int u = 0; u < 8; ++u) {
                    int lc  = g * 8 + u;
                    int off = (mat * 65536 + lc * 2048 + k * 2) ^ ((lc & 7) << 4);
                    *(f16*)(smem + off) = (f16)vals[u];
                }
            }
        }
    }

    // ---- gate-thread state (tid<128: one (batch-row, unit) pair each)
    int grow = 0, gcol = 0;
    float bz0 = 0, bz1 = 0, bz2 = 0, bz3 = 0;
    if (tid < 128) {
        grow = tid >> 3;
        gcol = base + (tid & 7);
        bz0 = bias[layer * 4096 + gcol];
        bz1 = bias[layer * 4096 + 1024 + gcol];
        bz2 = bias[layer * 4096 + 2048 + gcol];
        bz3 = bias[layer * 4096 + 3072 + gcol];
    }
    float creg = 0.f;

    const int arow = lane & 15;          // batch row for fragments
    const int koff = (lane >> 4) * 8;    // lane k offset within 32
    const float* gam = gamma + layer * 1024;
    const float* bet = beta  + layer * 1024;

    cg::grid_group grid = cg::this_grid();
    __syncthreads();   // Wlds ready

    for (int tick = 0; tick <= 512; ++tick) {
        const int  step   = layer ? tick - 1 : tick;
        const bool active = layer ? (tick >= 1) : (tick < 512);
        if (active) {
            if (layer) {
                // LayerNorm stats of inp1[step&1] (block-redundant)
                const float* ip = inp1buf + (step & 1) * (16 * 1024);
                int row = tid >> 4, seg = tid & 15;
                const float4* p = (const float4*)(ip + row * 1024 + seg * 64);
                float sum = 0.f, sq = 0.f;
                #pragma unroll
                for (int j = 0; j < 16; ++j) {
                    float4 v = p[j];
                    sum += v.x + v.y + v.z + v.w;
                    sq  += v.x*v.x + v.y*v.y + v.z*v.z + v.w*v.w;
                }
                #pragma unroll
                for (int m = 1; m < 16; m <<= 1) {
                    sum += __shfl_xor(sum, m);
                    sq  += __shfl_xor(sq,  m);
                }
                if (seg == 0) {
                    float mu  = sum * (1.f / 1024.f);
                    float var = sq  * (1.f / 1024.f) - mu * mu;
                    stats[row * 2]     = mu;
                    stats[row * 2 + 1] = rsqrtf(var + LN_EPS);
                }
                __syncthreads();
            }

            float mu, rsig;
            const float* xrow;
            const f16*   hrow;
            if (layer == 0) {
                int tok = x[arow * 512 + step];
                float2 st = xstat[step * 16 + arow];
                mu = st.x; rsig = st.y;
                xrow = embed + (size_t)tok * 1024;
                hrow = h0buf + ((step + 1) & 1) * (16 * 1024) + arow * 1024;
            } else {
                mu = stats[arow * 2]; rsig = stats[arow * 2 + 1];
                xrow = inp1buf + (step & 1) * (16 * 1024) + arow * 1024;
                hrow = h1buf + ((step + 1) & 1) * (16 * 1024) + arow * 1024;
            }

            f32x4 acc0 = {0.f, 0.f, 0.f, 0.f};
            f32x4 acc1 = {0.f, 0.f, 0.f, 0.f};
            const int lcA = lane & 15;
            #pragma unroll
            for (int ks = 0; ks < 8; ++ks) {
                const int k0 = wv * 256 + ks * 32 + koff;
                float4 e0 = *(const float4*)(xrow + k0);
                float4 e1 = *(const float4*)(xrow + k0 + 4);
                float4 g0 = *(const float4*)(gam + k0);
                float4 g1 = *(const float4*)(gam + k0 + 4);
                float4 q0 = *(const float4*)(bet + k0);
                float4 q1 = *(const float4*)(bet + k0 + 4);
                f16x8 xa;
                xa[0] = (f16)((e0.x - mu) * rsig * g0.x + q0.x);
                xa[1] = (f16)((e0.y - mu) * rsig * g0.y + q0.y);
                xa[2] = (f16)((e0.z - mu) * rsig * g0.z + q0.z);
                xa[3] = (f16)((e0.w - mu) * rsig * g0.w + q0.w);
                xa[4] = (f16)((e1.x - mu) * rsig * g1.x + q1.x);
                xa[5] = (f16)((e1.y - mu) * rsig * g1.y + q1.y);
                xa[6] = (f16)((e1.z - mu) * rsig * g1.z + q1.z);
                xa[7] = (f16)((e1.w - mu) * rsig * g1.w + q1.w);
                f16x8 ha = *(const f16x8*)(hrow + k0);

                int swz0 = (lcA * 2048 + k0 * 2) ^ ((lcA & 7) << 4);
                f16x8 wx0 = *(const f16x8*)(smem + swz0);
                f16x8 wh0 = *(const f16x8*)(smem + 65536 + swz0);
                acc0 = __builtin_amdgcn_mfma_f32_16x16x32_f16(xa, wx0, acc0, 0, 0, 0);
                acc0 = __builtin_amdgcn_mfma_f32_16x16x32_f16(ha, wh0, acc0, 0, 0, 0);
                int lc1  = 16 + lcA;
                int swz1 = (lc1 * 2048 + k0 * 2) ^ ((lc1 & 7) << 4);
                f16x8 wx1 = *(const f16x8*)(smem + swz1);
                f16x8 wh1 = *(const f16x8*)(smem + 65536 + swz1);
                acc1 = __builtin_amdgcn_mfma_f32_16x16x32_f16(xa, wx1, acc1, 0, 0, 0);
                acc1 = __builtin_amdgcn_mfma_f32_16x16x32_f16(ha, wh1, acc1, 0, 0, 0);
            }

            // K-split partial reduction through LDS
            #pragma unroll
            for (int r = 0; r < 4; ++r) {
                int row = (lane >> 4) * 4 + r;
                zred[wv * 512 + row * 32 + (lane & 15)]      = acc0[r];
                zred[wv * 512 + row * 32 + 16 + (lane & 15)] = acc1[r];
            }
            __syncthreads();

            if (tid < 128) {
                int zb = grow * 32 + (tid & 7);
                float zi = bz0, zf = bz1, zo = bz2, zg = bz3;
                #pragma unroll
                for (int w = 0; w < 4; ++w) {
                    zi += zred[w * 512 + zb];
                    zf += zred[w * 512 + zb + 8];
                    zo += zred[w * 512 + zb + 16];
                    zg += zred[w * 512 + zb + 24];
                }
                float si = 1.f / (1.f + expf(-zi));
                float sf = 1.f / (1.f + expf(-zf));
                float so = 1.f / (1.f + expf(-zo));
                float cn = sf * creg + si * tanhf(zg);
                float hn = so * tanhf(cn);
                creg = cn;
                if (layer == 0) {
                    int tok = x[grow * 512 + step];
                    float xe = embed[(size_t)tok * 1024 + gcol];
                    inp1buf[(step & 1) * (16 * 1024) + grow * 1024 + gcol] = hn + xe;
                    h0buf[(step & 1) * (16 * 1024) + grow * 1024 + gcol]   = (f16)hn;
                } else {
                    h1buf[(step & 1) * (16 * 1024) + grow * 1024 + gcol]   = (f16)hn;
                    hseq[((size_t)step * 16 + grow) * 1024 + gcol]          = (f16)hn;
                }
            }
        }
        grid.sync();
    }

    if (tid < 128)
        cout[layer * (16 * 1024) + grow * 1024 + gcol] = creg;
}

// ---------------------------------------------------------------------------
// D: logits = h_seq(f16 [8192][1024]) @ embed(f16 [32000][1024])^T -> fp32 'bsv'
// 128x128 tile, BK=64, 4 waves (2x2 of 64x64), XOR-swizzled LDS, reg-staged.
__global__ void __launch_bounds__(256)
k_logits(const f16* __restrict__ A, const f16* __restrict__ Bm, float* __restrict__ out) {
    __shared__ f16 Asm[128 * 64];
    __shared__ f16 Bsm[128 * 64];
    const int nwg = gridDim.x;                       // 16000, %8==0
    int swz = (blockIdx.x % 8) * (nwg / 8) + blockIdx.x / 8;
    const int tm = swz / 250;
    const int tn = swz % 250;
    const int tid = threadIdx.x;
    const int lane = tid & 63;
    const int wv = tid >> 6;
    const int wm = wv >> 1, wn = wv & 1;

    f32x4 acc[4][4] = {};
    const f16* Ab = A  + (size_t)(tm * 128) * 1024;
    const f16* Bb = Bm + (size_t)(tn * 128) * 1024;

    for (int kt = 0; kt < 16; ++kt) {
        uint4 ra[4], rb[4];
        #pragma unroll
        for (int j = 0; j < 4; ++j) {
            int c = tid + j * 256;            // chunk 0..1023
            int row = c >> 3, slot = c & 7;
            ra[j] = *(const uint4*)(Ab + (size_t)row * 1024 + kt * 64 + slot * 8);
            rb[j] = *(const uint4*)(Bb + (size_t)row * 1024 + kt * 64 + slot * 8);
        }
        __syncthreads();
        #pragma unroll
        for (int j = 0; j < 4; ++j) {
            int c = tid + j * 256;
            int row = c >> 3, slot = c & 7;
            int off = row * 128 + ((slot ^ (row & 7)) << 4);
            *(uint4*)((char*)Asm + off) = ra[j];
            *(uint4*)((char*)Bsm + off) = rb[j];
        }
        __syncthreads();
        #pragma unroll
        for (int ks = 0; ks < 2; ++ks) {
            f16x8 af[4], bf[4];
            #pragma unroll
            for (int mi = 0; mi < 4; ++mi) {
                int row = wm * 64 + mi * 16 + (lane & 15);
                int slot = ks * 4 + (lane >> 4);
                af[mi] = *(const f16x8*)((const char*)Asm + row * 128 + ((slot ^ (row & 7)) << 4));
            }
            #pragma unroll
            for (int ni = 0; ni < 4; ++ni) {
                int row = wn * 64 + ni * 16 + (lane & 15);
                int slot = ks * 4 + (lane >> 4);
                bf[ni] = *(const f16x8*)((const char*)Bsm + row * 128 + ((slot ^ (row & 7)) << 4));
            }
            #pragma unroll
            for (int mi = 0; mi < 4; ++mi)
                #pragma unroll
                for (int ni = 0; ni < 4; ++ni)
                    acc[mi][ni] = __builtin_amdgcn_mfma_f32_16x16x32_f16(af[mi], bf[ni], acc[mi][ni], 0, 0, 0);
        }
    }

    // epilogue: rows m = s*16 + b ; out[b][s][v]
    #pragma unroll
    for (int mi = 0; mi < 4; ++mi) {
        int m16 = tm * 128 + wm * 64 + mi * 16;    // multiple of 16
        int s = m16 >> 4;
        #pragma unroll
        for (int ni = 0; ni < 4; ++ni) {
            int v = tn * 128 + wn * 64 + ni * 16 + (lane & 15);
            #pragma unroll
            for (int r = 0; r < 4; ++r) {
                int b = (lane >> 4) * 4 + r;
                out[((size_t)b * 512 + s) * 32000 + v] = acc[mi][ni][r];
            }
        }
    }
}

// ---------------------------------------------------------------------------
extern "C" void kernel_launch(void* const* d_in, const int* in_sizes, int n_in,
                              void* d_out, int out_size, void* d_ws, size_t ws_size,
                              hipStream_t stream) {
    const int*   x     = (const int*)d_in[0];
    const float* embed = (const float*)d_in[1];
    const float* gamma = (const float*)d_in[2];
    const float* beta  = (const float*)d_in[3];
    const float* W     = (const float*)d_in[4];
    const float* bias  = (const float*)d_in[5];
    float* out = (float*)d_out;

    char* p = (char*)d_ws;
    f16*    embed_f16 = (f16*)p;    p += (size_t)32000 * 1024 * 2;   // 65,536,000
    f16*    hseq      = (f16*)p;    p += (size_t)512 * 16 * 1024 * 2; // 16,777,216
    float2* xstat     = (float2*)p; p += 8192 * 8;                    // 65,536
    f16*    h0buf     = (f16*)p;    p += 2 * 16 * 1024 * 2;           // 65,536
    f16*    h1buf     = (f16*)p;    p += 2 * 16 * 1024 * 2;           // 65,536
    float*  inp1buf   = (float*)p;  p += 2 * 16 * 1024 * 4;           // 131,072

    k_cvt<<<2048, 256, 0, stream>>>(embed, embed_f16, 32000 * 1024 / 4);
    k_xstat<<<2048, 256, 0, stream>>>(x, embed, xstat);
    hipMemsetAsync(h0buf, 0, 131072, stream);   // zero h0[2] + h1[2] (contiguous)

    hipFuncSetAttribute((const void*)k_recur,
                        hipFuncAttributeMaxDynamicSharedMemorySize, 139392);
    void* args[] = { (void*)&x, (void*)&embed, (void*)&gamma, (void*)&beta,
                     (void*)&W, (void*)&bias, (void*)&xstat,
                     (void*)&h0buf, (void*)&h1buf, (void*)&inp1buf,
                     (void*)&hseq, (void*)&out };
    hipLaunchCooperativeKernel((const void*)k_recur, dim3(256), dim3(256),
                               args, 139392, stream);

    k_logits<<<16000, 256, 0, stream>>>(hseq, embed_f16, out + 32768);
}